// Round 2
// baseline (472.893 us; speedup 1.0000x reference)
//
#include <hip/hip_runtime.h>
#include <hip/hip_cooperative_groups.h>

namespace cg = cooperative_groups;

// Problem constants: B=4, M=512, L=31, S=2, W=M+L-1=542
#define CB 4
#define CM 512
#define CL 31
#define CW 542
#define SLAB  (CM * CL)      // 15872 floats of H per (b,m) slab
#define SLAB4 (SLAB / 4)     // 3968 float4
#define NBM   (CB * CM)      // 2048 slabs
#define CPAD  543            // ysum copy stride (543 mod 32 = 31 -> bank-spread)

typedef float f32x4 __attribute__((ext_vector_type(4)));

// X[b,m,n,l] = H[b,m,n,l] * (Y[b,m,n+l,0] + Y[b,m,n+l,1]); out = X / max(X)
// One block per (b,m) slab, 256 threads, H/out streamed as float4.
//
// ysum staged as FOUR replicated copies at stride 543 (543 mod 32 = 31);
// lane uses copy (tid>>3)&3 -> stride-4 gather is exactly 2-way (= free).
//
// Index math: f = 4*tid + 1024*k; 1024 = 33*31 + 1, so l = f%31 advances +1
// per iteration; carried incrementally, no int division in the loop.

__device__ __forceinline__ void stage_ysum(const float* __restrict__ Y, int bm,
                                           float* __restrict__ ys) {
    const float2* y2 = (const float2*)(Y + (size_t)bm * (CW * 2));
    for (int j = threadIdx.x; j < CW; j += 256) {
        float2 v = y2[j];
        float s = v.x + v.y;
        ys[j]            = s;
        ys[j + CPAD]     = s;
        ys[j + 2 * CPAD] = s;
        ys[j + 3 * CPAD] = s;
    }
}

struct IdxState {
    int l0;   // f % 31 for the quad base
    int i0;   // n0 + l0 (ysum index of the quad's first element)
};

__device__ __forceinline__ IdxState idx_init(int tid) {
    unsigned f = 4u * (unsigned)tid;
    unsigned n = f / 31u;            // one division, outside the loop
    IdxState s;
    s.l0 = (int)(f - n * 31u);
    s.i0 = (int)n + s.l0;
    return s;
}

__device__ __forceinline__ void idx_quad(const IdxState& s,
                                         int& i0, int& i1, int& i2, int& i3) {
    // element j wraps iff l0 >= 31-j (at most one wrap per quad, L=31>4)
    i0 = s.i0;
    i1 = s.i0 + ((s.l0 >= 30) ? 1 - 30 : 1);
    i2 = s.i0 + ((s.l0 >= 29) ? 2 - 30 : 2);
    i3 = s.i0 + ((s.l0 >= 28) ? 3 - 30 : 3);
}

__device__ __forceinline__ void idx_step(IdxState& s) {
    // f += 1024 -> l0 += 1 (mod 31); i0 += 34 (or +4 on wrap)
    bool w = (s.l0 == 30);
    s.i0 += w ? 4 : 34;
    s.l0  = w ? 0 : (s.l0 + 1);
}

__device__ __forceinline__ float slab_max(const f32x4* __restrict__ h4,
                                          const float* __restrict__ ys, int tid) {
    IdxState st = idx_init(tid);
    float mx = 0.0f;   // all X >= 0 (H,Y uniform [0,1))
#pragma unroll 5
    for (int k = 0; k < 15; ++k) {
        f32x4 h = h4[tid + (k << 8)];
        int i0, i1, i2, i3;
        idx_quad(st, i0, i1, i2, i3);
        mx = fmaxf(mx, fmaxf(fmaxf(h[0] * ys[i0], h[1] * ys[i1]),
                             fmaxf(h[2] * ys[i2], h[3] * ys[i3])));
        idx_step(st);
    }
    if (tid < 128) {   // tail half-pass: SLAB4 = 15.5 * 256
        f32x4 h = h4[tid + 15 * 256];
        int i0, i1, i2, i3;
        idx_quad(st, i0, i1, i2, i3);
        mx = fmaxf(mx, fmaxf(fmaxf(h[0] * ys[i0], h[1] * ys[i1]),
                             fmaxf(h[2] * ys[i2], h[3] * ys[i3])));
    }
    return mx;
}

// Pass 2: nontemporal H loads (hit L3 then evict; never re-read) and
// nontemporal out stores (don't allocate in L2/L3 -> H stays resident).
__device__ __forceinline__ void slab_scale(const f32x4* __restrict__ h4,
                                           f32x4* __restrict__ o4,
                                           const float* __restrict__ ys,
                                           int tid, float inv) {
    IdxState st = idx_init(tid);
#pragma unroll 5
    for (int k = 0; k < 15; ++k) {
        f32x4 h = __builtin_nontemporal_load(&h4[tid + (k << 8)]);
        int i0, i1, i2, i3;
        idx_quad(st, i0, i1, i2, i3);
        f32x4 o;
        o[0] = h[0] * ys[i0] * inv;
        o[1] = h[1] * ys[i1] * inv;
        o[2] = h[2] * ys[i2] * inv;
        o[3] = h[3] * ys[i3] * inv;
        __builtin_nontemporal_store(o, &o4[tid + (k << 8)]);
        idx_step(st);
    }
    if (tid < 128) {
        f32x4 h = __builtin_nontemporal_load(&h4[tid + 15 * 256]);
        int i0, i1, i2, i3;
        idx_quad(st, i0, i1, i2, i3);
        f32x4 o;
        o[0] = h[0] * ys[i0] * inv;
        o[1] = h[1] * ys[i1] * inv;
        o[2] = h[2] * ys[i2] * inv;
        o[3] = h[3] * ys[i3] * inv;
        __builtin_nontemporal_store(o, &o4[tid + 15 * 256]);
    }
}

__device__ __forceinline__ float block_reduce_max(float v, float* smax, int tid) {
#pragma unroll
    for (int off = 32; off > 0; off >>= 1)
        v = fmaxf(v, __shfl_down(v, off, 64));
    if ((tid & 63) == 0) smax[tid >> 6] = v;
    __syncthreads();
    return fmaxf(fmaxf(smax[0], smax[1]), fmaxf(smax[2], smax[3]));
}

// ---------- fused cooperative kernel (primary path) ----------
__global__ __launch_bounds__(256, 8) void cassi_fused(
    const float* __restrict__ Y,
    const float* __restrict__ H,
    float* __restrict__ blockmax,
    float* __restrict__ out)
{
    __shared__ float ysum[4 * CPAD];
    __shared__ float smax[4];
    const int bm  = blockIdx.x;
    const int tid = threadIdx.x;

    stage_ysum(Y, bm, ysum);
    __syncthreads();

    const float* ys = ysum + ((tid >> 3) & 3) * CPAD;
    const f32x4* h4 = (const f32x4*)(H + (size_t)bm * SLAB);

    float mx   = slab_max(h4, ys, tid);
    float bmax = block_reduce_max(mx, smax, tid);
    if (tid == 0) blockmax[bm] = bmax;

    cg::this_grid().sync();   // also block-syncs: smax safe to reuse below

    float m = 0.0f;
    for (int j = tid; j < NBM; j += 256) m = fmaxf(m, blockmax[j]);
    const float inv = 1.0f / block_reduce_max(m, smax, tid);

    slab_scale(h4, (f32x4*)(out + (size_t)bm * SLAB), ys, tid, inv);
}

// ---------- fallback two-kernel path ----------
__global__ __launch_bounds__(256, 8) void cassi_max_k(
    const float* __restrict__ Y,
    const float* __restrict__ H,
    float* __restrict__ blockmax)
{
    __shared__ float ysum[4 * CPAD];
    __shared__ float smax[4];
    const int bm  = blockIdx.x;
    const int tid = threadIdx.x;

    stage_ysum(Y, bm, ysum);
    __syncthreads();

    const float* ys = ysum + ((tid >> 3) & 3) * CPAD;
    const f32x4* h4 = (const f32x4*)(H + (size_t)bm * SLAB);

    float bmax = block_reduce_max(slab_max(h4, ys, tid), smax, tid);
    if (tid == 0) blockmax[bm] = bmax;
}

__global__ __launch_bounds__(256, 8) void cassi_out_k(
    const float* __restrict__ Y,
    const float* __restrict__ H,
    const float* __restrict__ blockmax,
    float* __restrict__ out)
{
    __shared__ float ysum[4 * CPAD];
    __shared__ float smax[4];
    const int bm  = blockIdx.x;
    const int tid = threadIdx.x;

    stage_ysum(Y, bm, ysum);

    float m = 0.0f;
    for (int j = tid; j < NBM; j += 256) m = fmaxf(m, blockmax[j]);
#pragma unroll
    for (int off = 32; off > 0; off >>= 1)
        m = fmaxf(m, __shfl_down(m, off, 64));
    if ((tid & 63) == 0) smax[tid >> 6] = m;
    __syncthreads();   // covers both ysum and smax stores
    const float inv = 1.0f / fmaxf(fmaxf(smax[0], smax[1]), fmaxf(smax[2], smax[3]));

    const float* ys = ysum + ((tid >> 3) & 3) * CPAD;
    const f32x4* h4 = (const f32x4*)(H + (size_t)bm * SLAB);
    slab_scale(h4, (f32x4*)(out + (size_t)bm * SLAB), ys, tid, inv);
}

extern "C" void kernel_launch(void* const* d_in, const int* in_sizes, int n_in,
                              void* d_out, int out_size, void* d_ws, size_t ws_size,
                              hipStream_t stream)
{
    (void)in_sizes; (void)n_in; (void)out_size; (void)ws_size;
    const float* Y = (const float*)d_in[0];   // (B, M, W, S)
    const float* H = (const float*)d_in[1];   // (B, M, M, L)
    float* out = (float*)d_out;               // (B, M, M, L)
    float* blockmax = (float*)d_ws;           // 2048 floats; fully written before read

    void* args[] = { (void*)&Y, (void*)&H, (void*)&blockmax, (void*)&out };
    hipError_t err = hipLaunchCooperativeKernel((const void*)cassi_fused,
                                                dim3(NBM), dim3(256), args, 0, stream);
    if (err != hipSuccess) {
        // cooperative launch unavailable -> two-kernel fallback
        cassi_max_k<<<NBM, 256, 0, stream>>>(Y, H, blockmax);
        cassi_out_k<<<NBM, 256, 0, stream>>>(Y, H, blockmax, out);
    }
}

// Round 3
// 252.675 us; speedup vs baseline: 1.8715x; 1.8715x over previous
//
#include <hip/hip_runtime.h>

// Problem constants: B=4, M=512, L=31, S=2, W=M+L-1=542
#define CB 4
#define CM 512
#define CL 31
#define CW 542
#define SLAB  (CM * CL)      // 15872 floats of H per (b,m) slab
#define SLAB4 (SLAB / 4)     // 3968 float4
#define NBM   (CB * CM)      // 2048 slabs
#define CPAD  543            // ysum copy stride (543 mod 32 = 31 -> bank-spread)

typedef float f32x4 __attribute__((ext_vector_type(4)));

// X[b,m,n,l] = H[b,m,n,l] * (Y[b,m,n+l,0] + Y[b,m,n+l,1]); out = X / max(X)
// Two kernels (max, then scale); one block per (b,m) slab, 256 threads.
// Round-2 cooperative fusion measured 300us (grid.sync serialization) -> reverted.
//
// ysum staged as FOUR replicated copies at stride 543 (543 mod 32 = 31);
// lane uses copy (tid>>3)&3 -> stride-4 gather is exactly 2-way (= free).
//
// Index math: f = 4*tid + 1024*k; 1024 = 33*31 + 1, so l = f%31 advances +1
// per iteration; carried incrementally, no int division in the loop.
//
// grid == 8 blocks/CU * 256 CU exactly -> one block-wave; staging latency is
// not hidden by other blocks, so the first two H quads are loaded BEFORE the
// staging barrier to overlap it.

__device__ __forceinline__ void stage_ysum(const float* __restrict__ Y, int bm,
                                           float* __restrict__ ys) {
    const float2* y2 = (const float2*)(Y + (size_t)bm * (CW * 2));
    for (int j = threadIdx.x; j < CW; j += 256) {
        float2 v = y2[j];
        float s = v.x + v.y;
        ys[j]            = s;
        ys[j + CPAD]     = s;
        ys[j + 2 * CPAD] = s;
        ys[j + 3 * CPAD] = s;
    }
}

struct IdxState {
    int l0;   // f % 31 for the quad base
    int i0;   // n0 + l0 (ysum index of the quad's first element)
};

__device__ __forceinline__ IdxState idx_init(int tid) {
    unsigned f = 4u * (unsigned)tid;
    unsigned n = f / 31u;            // one division, outside the loop
    IdxState s;
    s.l0 = (int)(f - n * 31u);
    s.i0 = (int)n + s.l0;
    return s;
}

__device__ __forceinline__ void idx_quad(const IdxState& s,
                                         int& i0, int& i1, int& i2, int& i3) {
    // element j wraps iff l0 >= 31-j (at most one wrap per quad, L=31>4)
    i0 = s.i0;
    i1 = s.i0 + ((s.l0 >= 30) ? 1 - 30 : 1);
    i2 = s.i0 + ((s.l0 >= 29) ? 2 - 30 : 2);
    i3 = s.i0 + ((s.l0 >= 28) ? 3 - 30 : 3);
}

__device__ __forceinline__ void idx_step(IdxState& s) {
    // f += 1024 -> l0 += 1 (mod 31); i0 += 34 (or +4 on wrap)
    bool w = (s.l0 == 30);
    s.i0 += w ? 4 : 34;
    s.l0  = w ? 0 : (s.l0 + 1);
}

__device__ __forceinline__ float quad_max(const f32x4& h, const float* __restrict__ ys,
                                          const IdxState& st) {
    int i0, i1, i2, i3;
    idx_quad(st, i0, i1, i2, i3);
    return fmaxf(fmaxf(h[0] * ys[i0], h[1] * ys[i1]),
                 fmaxf(h[2] * ys[i2], h[3] * ys[i3]));
}

__global__ __launch_bounds__(256, 8) void cassi_max_k(
    const float* __restrict__ Y,
    const float* __restrict__ H,
    float* __restrict__ blockmax)
{
    __shared__ float ysum[4 * CPAD];
    __shared__ float smax[4];
    const int bm  = blockIdx.x;
    const int tid = threadIdx.x;

    const f32x4* h4 = (const f32x4*)(H + (size_t)bm * SLAB);
    // prefetch first two quads: HBM latency overlaps the staging barrier
    f32x4 h0 = h4[tid];
    f32x4 h1 = h4[tid + 256];

    stage_ysum(Y, bm, ysum);
    __syncthreads();

    const float* ys = ysum + ((tid >> 3) & 3) * CPAD;
    IdxState st = idx_init(tid);
    float mx = 0.0f;   // all X >= 0 (H,Y uniform [0,1))

    mx = fmaxf(mx, quad_max(h0, ys, st)); idx_step(st);
    mx = fmaxf(mx, quad_max(h1, ys, st)); idx_step(st);

#pragma unroll 5
    for (int k = 2; k < 15; ++k) {
        f32x4 h = h4[tid + (k << 8)];
        mx = fmaxf(mx, quad_max(h, ys, st));
        idx_step(st);
    }
    if (tid < 128) {   // tail half-pass: SLAB4 = 15.5 * 256
        f32x4 h = h4[tid + 15 * 256];
        mx = fmaxf(mx, quad_max(h, ys, st));
    }

#pragma unroll
    for (int off = 32; off > 0; off >>= 1)
        mx = fmaxf(mx, __shfl_down(mx, off, 64));
    if ((tid & 63) == 0) smax[tid >> 6] = mx;
    __syncthreads();
    if (tid == 0)
        blockmax[bm] = fmaxf(fmaxf(smax[0], smax[1]), fmaxf(smax[2], smax[3]));
}

__global__ __launch_bounds__(256, 8) void cassi_out_k(
    const float* __restrict__ Y,
    const float* __restrict__ H,
    const float* __restrict__ blockmax,
    float* __restrict__ out)
{
    __shared__ float ysum[4 * CPAD];
    __shared__ float smax[4];
    const int bm  = blockIdx.x;
    const int tid = threadIdx.x;

    const f32x4* h4 = (const f32x4*)(H + (size_t)bm * SLAB);
    f32x4 h0 = h4[tid];          // prefetch across the staging prologue
    f32x4 h1 = h4[tid + 256];

    stage_ysum(Y, bm, ysum);

    // global max = reduce of 2048 per-block maxima (L2-broadcast, 8 loads/thr)
    float m = 0.0f;
    for (int j = tid; j < NBM; j += 256) m = fmaxf(m, blockmax[j]);
#pragma unroll
    for (int off = 32; off > 0; off >>= 1)
        m = fmaxf(m, __shfl_down(m, off, 64));
    if ((tid & 63) == 0) smax[tid >> 6] = m;
    __syncthreads();   // covers ysum and smax stores
    const float inv = 1.0f / fmaxf(fmaxf(smax[0], smax[1]), fmaxf(smax[2], smax[3]));

    const float* ys = ysum + ((tid >> 3) & 3) * CPAD;
    f32x4* o4 = (f32x4*)(out + (size_t)bm * SLAB);
    IdxState st = idx_init(tid);

    // nontemporal stores: out is never re-read; don't let write-allocate
    // evict the L3-resident H (H + out = 260 MB > 256 MB L3). H loads stay
    // plain (they're the lines we want kept).
    {
        int i0, i1, i2, i3;
        idx_quad(st, i0, i1, i2, i3);
        f32x4 o = { h0[0] * ys[i0] * inv, h0[1] * ys[i1] * inv,
                    h0[2] * ys[i2] * inv, h0[3] * ys[i3] * inv };
        __builtin_nontemporal_store(o, &o4[tid]);
        idx_step(st);
    }
    {
        int i0, i1, i2, i3;
        idx_quad(st, i0, i1, i2, i3);
        f32x4 o = { h1[0] * ys[i0] * inv, h1[1] * ys[i1] * inv,
                    h1[2] * ys[i2] * inv, h1[3] * ys[i3] * inv };
        __builtin_nontemporal_store(o, &o4[tid + 256]);
        idx_step(st);
    }

#pragma unroll 5
    for (int k = 2; k < 15; ++k) {
        f32x4 h = h4[tid + (k << 8)];
        int i0, i1, i2, i3;
        idx_quad(st, i0, i1, i2, i3);
        f32x4 o = { h[0] * ys[i0] * inv, h[1] * ys[i1] * inv,
                    h[2] * ys[i2] * inv, h[3] * ys[i3] * inv };
        __builtin_nontemporal_store(o, &o4[tid + (k << 8)]);
        idx_step(st);
    }
    if (tid < 128) {
        f32x4 h = h4[tid + 15 * 256];
        int i0, i1, i2, i3;
        idx_quad(st, i0, i1, i2, i3);
        f32x4 o = { h[0] * ys[i0] * inv, h[1] * ys[i1] * inv,
                    h[2] * ys[i2] * inv, h[3] * ys[i3] * inv };
        __builtin_nontemporal_store(o, &o4[tid + 15 * 256]);
    }
}

extern "C" void kernel_launch(void* const* d_in, const int* in_sizes, int n_in,
                              void* d_out, int out_size, void* d_ws, size_t ws_size,
                              hipStream_t stream)
{
    (void)in_sizes; (void)n_in; (void)out_size; (void)ws_size;
    const float* Y = (const float*)d_in[0];   // (B, M, W, S)
    const float* H = (const float*)d_in[1];   // (B, M, M, L)
    float* out = (float*)d_out;               // (B, M, M, L)
    float* blockmax = (float*)d_ws;           // 2048 floats; fully written before read

    cassi_max_k<<<NBM, 256, 0, stream>>>(Y, H, blockmax);
    cassi_out_k<<<NBM, 256, 0, stream>>>(Y, H, blockmax, out);
}